// Round 8
// baseline (580.294 us; speedup 1.0000x reference)
//
#include <hip/hip_runtime.h>
#include <hip/hip_fp16.h>
#include <math.h>

#define NN      100000
#define EE      1600000
#define NPAIRS  800000
#define DIN     128
#define CC      16
#define NITERS  5
#define PPT     4                    // pairs per thread
#define NGRP    (NPAIRS / PPT)       // 200000 groups of 16 lanes
#define NEGLOGC (-2.772588722239781f)
#define QSCALE  128.0f               // agg fixed-point scale (u16 fields)
#define QINV    (1.0f / 128.0f)

typedef float  f4 __attribute__((ext_vector_type(4)));
typedef int    i2 __attribute__((ext_vector_type(2)));
typedef unsigned long long ull;

// ---------------------------------------------------------------------------
// helpers: fp16 <-> f32 (bit-level)
// ---------------------------------------------------------------------------
__device__ __forceinline__ unsigned short f2h(float f) {
    __half h = __float2half(f);
    return __half_as_ushort(h);
}
__device__ __forceinline__ float h2f(unsigned short u) {
    return __half2float(__ushort_as_half(u));
}
__device__ __forceinline__ unsigned int pack_h(float lo, float hi) {
    return (unsigned int)f2h(lo) | ((unsigned int)f2h(hi) << 16);
}

// ---------------------------------------------------------------------------
// fused setup: M = sigmoid(10*param); logb0 = log_softmax(x@W+b); agg16 = 0
// grid = 6250 blocks of 256 (covers NN*CC == 1.6M exactly)
// ---------------------------------------------------------------------------
__global__ __launch_bounds__(256) void k_setup(
    const float* __restrict__ x, const float* __restrict__ W,
    const float* __restrict__ b, const float* __restrict__ param,
    float* __restrict__ M, float* __restrict__ logb0,
    unsigned short* __restrict__ agg16)
{
    if (blockIdx.x == 0 && threadIdx.x < CC * (CC + 1) / 2) {
        int i = threadIdx.x;
        int r = 0;
        while ((r + 1) * (r + 2) / 2 <= i) ++r;
        int c = i - r * (r + 1) / 2;
        float z = param[i] * 10.0f;
        float s = 1.0f / (1.0f + __expf(-z));
        M[r * CC + c] = s;
        if (r != c) M[c * CC + r] = s;
    }

    int idx = blockIdx.x * 256 + threadIdx.x;
    agg16[idx] = 0;

    int node = idx >> 4;
    int cls  = idx & 15;
    const f4* xr4 = (const f4*)(x + (long)node * DIN);
    float acc = b[cls];
#pragma unroll 8
    for (int k4 = 0; k4 < DIN / 4; ++k4) {
        f4 xv = __builtin_nontemporal_load(xr4 + k4);   // x streamed once
        acc = fmaf(xv.x, W[(4 * k4 + 0) * CC + cls], acc);
        acc = fmaf(xv.y, W[(4 * k4 + 1) * CC + cls], acc);
        acc = fmaf(xv.z, W[(4 * k4 + 2) * CC + cls], acc);
        acc = fmaf(xv.w, W[(4 * k4 + 3) * CC + cls], acc);
    }
    float m = acc;
    for (int off = 8; off; off >>= 1) m = fmaxf(m, __shfl_xor(m, off, 16));
    float s = __expf(acc - m);
    for (int off = 8; off; off >>= 1) s += __shfl_xor(s, off, 16);
    logb0[idx] = acc - m - __logf(s);
}

// ---------------------------------------------------------------------------
// message update + scatter. 16 lanes per edge-pair (lane = class).
// Linear-space matvec:
//   S[c] = sum_k exp(t[k]) * M[k][c];  log_msg[c] = log S[c] - log(sum_c S[c])
// t in [-log C, ~7] -> exp fp32-safe; no max-subtraction needed.
// msg2[p*16+c] packs pair p both directions as fp16 {lo=edge 2p, hi=2p+1}.
// RD_MSG=false on iter 0 (msg == const -log C); WR_MSG=false on last iter.
//
// Scatter (fabric-BYTE-limited per round-7 A/B): messages are strictly
// negative with n >= ~-6, so q = round(-n*128) <= 1023 (clamped); max
// in-degree << 63 so per-node-class u16 sums can't overflow 65535.
// Pack 4 classes per u64 (4 x u16 fields): 8 u64 atomics per pair = 64 B
// payload (half of round 7's 128 B). agg16[n*16+c] (little-endian fields)
// holds class c's fixed-point sum; agg is 3.2 MB total.
// ---------------------------------------------------------------------------
template <bool RD_MSG, bool WR_MSG>
__global__ __launch_bounds__(256) void k_edges_t(
    const i2* __restrict__ esrc2, const i2* __restrict__ edst2,
    const float* __restrict__ logb, const float* __restrict__ Mg,
    unsigned int* __restrict__ msg2, ull* __restrict__ agg8)
{
    __shared__ float sM[CC * CC];
    __shared__ float sE[PPT][16 * 40];   // per-r slice, per-group stride 40
    sM[threadIdx.x] = Mg[threadIdx.x];   // blockDim == 256
    __syncthreads();

    const int lane = threadIdx.x & 15;
    const int gl   = threadIdx.x >> 4;           // group within block (0..15)
    const int g    = blockIdx.x * 16 + gl;       // global group

    float Hrow[CC];                              // M[k][lane] (symmetric)
#pragma unroll
    for (int k = 0; k < CC; ++k) Hrow[k] = sM[k * CC + lane];

    // hoist all streamed loads (independent -> deep pipelining)
    i2 s01[PPT], d01[PPT];
    unsigned int mold[PPT];
#pragma unroll
    for (int r = 0; r < PPT; ++r) {
        int p = g + r * NGRP;
        s01[r] = __builtin_nontemporal_load(esrc2 + p);
        d01[r] = __builtin_nontemporal_load(edst2 + p);
        if (RD_MSG)
            mold[r] = __builtin_nontemporal_load(msg2 + (long)p * CC + lane);
    }

    // exp(t) into per-r LDS slices
#pragma unroll
    for (int r = 0; r < PPT; ++r) {
        float lb0 = logb[(long)s01[r].x * CC + lane];
        float lb1 = logb[(long)s01[r].y * CC + lane];
        float mo0, mo1;
        if (RD_MSG) {
            mo0 = h2f((unsigned short)(mold[r] & 0xffffu));  // msg[2p]
            mo1 = h2f((unsigned short)(mold[r] >> 16));      // msg[2p+1]
        } else {
            mo0 = NEGLOGC; mo1 = NEGLOGC;
        }
        float* eb = sE[r] + gl * 40;
        eb[lane]      = __expf(lb0 - mo1);   // t = logb[src] - msg[reverse]
        eb[16 + lane] = __expf(lb1 - mo0);
    }

    // matvec + normalize + store + packed-u16-field scatter
#pragma unroll
    for (int r = 0; r < PPT; ++r) {
        const float* eb = sE[r] + gl * 40;
        float ev0[CC], ev1[CC];
        *(float4*)(ev0 +  0) = *(const float4*)(eb +  0);
        *(float4*)(ev0 +  4) = *(const float4*)(eb +  4);
        *(float4*)(ev0 +  8) = *(const float4*)(eb +  8);
        *(float4*)(ev0 + 12) = *(const float4*)(eb + 12);
        *(float4*)(ev1 +  0) = *(const float4*)(eb + 16);
        *(float4*)(ev1 +  4) = *(const float4*)(eb + 20);
        *(float4*)(ev1 +  8) = *(const float4*)(eb + 24);
        *(float4*)(ev1 + 12) = *(const float4*)(eb + 28);

        float S0 = 0.f, S1 = 0.f;
#pragma unroll
        for (int k = 0; k < CC; ++k) {
            S0 = fmaf(ev0[k], Hrow[k], S0);
            S1 = fmaf(ev1[k], Hrow[k], S1);
        }

        float T0 = S0, T1 = S1;
        for (int off = 8; off; off >>= 1) {
            T0 += __shfl_xor(T0, off, 16);
            T1 += __shfl_xor(T1, off, 16);
        }
        float n0 = __logf(S0) - __logf(T0);
        float n1 = __logf(S1) - __logf(T1);

        if (WR_MSG) {
            int p = g + r * NGRP;
            __builtin_nontemporal_store(pack_h(n0, n1),
                                        msg2 + (long)p * CC + lane);
        }

        // fixed-point u16-field packed scatter: 4 classes per u64 atomic
        unsigned int q0 = (unsigned int)fminf(fmaxf(-n0, 0.f) * QSCALE + 0.5f, 1023.f);
        unsigned int q1 = (unsigned int)fminf(fmaxf(-n1, 0.f) * QSCALE + 0.5f, 1023.f);
        // even lane c: a = {q(c), q(c+1)} as u16 pair (low = class c)
        unsigned int a0 = q0 | (__shfl_xor(q0, 1, 16) << 16);
        unsigned int a1 = q1 | (__shfl_xor(q1, 1, 16) << 16);
        unsigned int c20 = __shfl_xor(a0, 2, 16);
        unsigned int c21 = __shfl_xor(a1, 2, 16);
        int sub = lane & 3;
        if (sub == 0) {
            // classes 4j..4j+3 of edge0: low = a0(4j), high = a0(4j+2)=c20
            ull v = (ull)a0 | ((ull)c20 << 32);
            atomicAdd(&agg8[(long)d01[r].x * 4 + (lane >> 2)], v);
        } else if (sub == 2) {
            // classes 4j..4j+3 of edge1: low = a1(4j)=c21, high = a1(4j+2)
            ull v = (ull)c21 | ((ull)a1 << 32);
            atomicAdd(&agg8[(long)d01[r].y * 4 + (lane >> 2)], v);
        }
    }
}

// ---------------------------------------------------------------------------
// log_b = log_normalize(agg + log_b0); also resets agg for next iteration.
// agg16[n*16+c] holds the fixed-point class-c sum (little-endian u16 fields).
// ---------------------------------------------------------------------------
__global__ __launch_bounds__(256) void k_update(
    const float* __restrict__ logb0, unsigned short* __restrict__ agg16,
    float* __restrict__ out)
{
    int idx = blockIdx.x * blockDim.x + threadIdx.x;
    unsigned int q = agg16[idx];
    agg16[idx] = 0;
    float v = fmaf(-(float)q, QINV, logb0[idx]);
    float m = v;
    for (int off = 8; off; off >>= 1) m = fmaxf(m, __shfl_xor(m, off, 16));
    float s = __expf(v - m);
    for (int off = 8; off; off >>= 1) s += __shfl_xor(s, off, 16);
    out[idx] = v - m - __logf(s);
}

// ---------------------------------------------------------------------------
extern "C" void kernel_launch(void* const* d_in, const int* in_sizes, int n_in,
                              void* d_out, int out_size, void* d_ws, size_t ws_size,
                              hipStream_t stream)
{
    const float* x     = (const float*)d_in[0];
    const float* W     = (const float*)d_in[1];
    const float* b     = (const float*)d_in[2];
    const float* param = (const float*)d_in[3];
    const int*   eidx  = (const int*)d_in[4];
    const i2*    esrc2 = (const i2*)eidx;
    const i2*    edst2 = (const i2*)(eidx + EE);

    float* ws    = (float*)d_ws;
    float* M     = ws;                         // 256 floats
    float* logb0 = M     + 256;                // N*C
    float* logb  = logb0 + (long)NN * CC;      // N*C
    unsigned short* agg16 = (unsigned short*)(logb + (long)NN * CC); // N*C u16 (8B-aligned)
    ull*            agg8  = (ull*)agg16;
    unsigned int*   msg2  = (unsigned int*)(agg16 + (long)NN * CC);  // NPAIRS*C u32

    k_setup<<<NN * CC / 256, 256, 0, stream>>>(x, W, b, param, M, logb0, agg16);

    const float* curb = logb0;
    for (int it = 0; it < NITERS; ++it) {
        if (it == 0)
            k_edges_t<false, true><<<NGRP / 16, 256, 0, stream>>>(
                esrc2, edst2, curb, M, msg2, agg8);
        else if (it == NITERS - 1)
            k_edges_t<true, false><<<NGRP / 16, 256, 0, stream>>>(
                esrc2, edst2, curb, M, msg2, agg8);
        else
            k_edges_t<true, true><<<NGRP / 16, 256, 0, stream>>>(
                esrc2, edst2, curb, M, msg2, agg8);
        float* dst = (it == NITERS - 1) ? (float*)d_out : logb;
        k_update<<<NN * CC / 256, 256, 0, stream>>>(logb0, agg16, dst);
        curb = dst;
    }
}